// Round 16
// baseline (210.000 us; speedup 1.0000x reference)
//
#include <hip/hip_runtime.h>
#include <hip/hip_bf16.h>

// EPN layer: B=8, N=256, F=32, E_DIM=8, HID=32, IN_DIM=74, T=3
// ROUND 16: ONE persistent launch = r15 wave-owns-i body + r7-validated
// manual grid barrier. Grid 512 @ launch_bounds(256,2) = exactly 2 blocks/CU
// -> all 512 co-resident BY CONSTRUCTION (LDS 52.5KB caps 3/CU; VGPR<=256):
// gbar cannot deadlock. Each block owns the same 4 i for all 3 t (NO runtime
// pair loop -> avoids r10's VGPR-collapse). Pre folded into phase 0; e/mn
// staging is t-invariant -> staged ONCE (was 3x). Per t: sxJ/qL/frag reload,
// one __syncthreads, r15-verbatim hot loop (transposed layer-1 MFMA, K=16
// layer-2 no-exchange, fused epilogue), wave-local reduce, gbar.
// Rationale: r9..r15 plateau at ~52.5us with bodies modeling at 4-6us/main
// => ~35-40us is per-dispatch drain/ramp across 4 serialized graph nodes.
// This removes 3 of 4 nodes.

typedef __attribute__((ext_vector_type(8))) short short8;
typedef __attribute__((ext_vector_type(4))) short short4v;
typedef __attribute__((ext_vector_type(4))) float f32x4;
union U4S8 { uint4 u; short8 s; };
union U2S4 { uint2 u; short4v s; };
#define F4(p) (*(const float4*)(p))

#if defined(__HIP_DEVICE_COMPILE__)
# if __has_builtin(__builtin_amdgcn_mfma_f32_16x16x16bf16_1k)
#  define MFMA16(a,b,c) __builtin_amdgcn_mfma_f32_16x16x16bf16_1k(a,b,c,0,0,0)
# elif __has_builtin(__builtin_amdgcn_mfma_f32_16x16x16_bf16)
#  define MFMA16(a,b,c) __builtin_amdgcn_mfma_f32_16x16x16_bf16(a,b,c,0,0,0)
# else
#  error "no 16x16x16 bf16 MFMA builtin on this target"
# endif
#else
# define MFMA16(a,b,c) (f32x4{0.f,0.f,0.f,0.f})
#endif

__device__ __forceinline__ unsigned pkbf2(float lo, float hi) {
    unsigned a = __bfloat16_as_ushort(__float2bfloat16(lo));
    unsigned b = __bfloat16_as_ushort(__float2bfloat16(hi));
    return a | (b << 16);
}
__device__ __forceinline__ float bf2f(unsigned short u) {
    return __uint_as_float(((unsigned)u) << 16);
}

// r7-validated grid barrier (monotone counter in ws, memset-reset per call)
__device__ __forceinline__ void gbar(unsigned* bar, unsigned target) {
    __syncthreads();                 // compiler drains vmcnt before s_barrier
    if (threadIdx.x == 0) {
        __threadfence();             // release (device scope)
        atomicAdd(bar, 1u);
        while (__hip_atomic_load(bar, __ATOMIC_ACQUIRE,
                                 __HIP_MEMORY_SCOPE_AGENT) < target)
            __builtin_amdgcn_s_sleep(2);
        __threadfence();             // acquire
    }
    __syncthreads();
}

__global__ __launch_bounds__(256, 2) void epn_fused(
    const float* __restrict__ h, const float* __restrict__ e,
    const float* __restrict__ q0, const float* __restrict__ mask,
    const float* __restrict__ W1, const float* __restrict__ b1,
    const float* __restrict__ W2, const float* __restrict__ b2,
    const float* __restrict__ W3,
    unsigned short* __restrict__ basePbf, unsigned short* __restrict__ baseQbf,
    uint2* __restrict__ W2T16, uint4* __restrict__ WA,
    float* __restrict__ qA, float* __restrict__ qB, float* __restrict__ qOut,
    unsigned* __restrict__ bar)
{
    __shared__ uint4 sxJ[8][256];      // J bases (t-dep): 0-3 baseQ, 4-7 baseP
    __shared__ uint4 se[4][256];       // e rows bf16 per wave/i (t-invariant)
    __shared__ float mnL[4][256];      // mask*near per (i,j)  (t-invariant)
    __shared__ unsigned short qL[256]; // q_j bf16 (t-dep)

    // XCD-bijective swizzle (512 = 8*64): XCD k owns batch b=k
    const int orig = blockIdx.x;
    const int swz  = (orig & 7) * 64 + (orig >> 3);
    const int b    = swz >> 6;
    const int bi0  = b*256 + (swz & 63)*4;
    const int tid = threadIdx.x, j = tid;
    const int lane = tid & 63, w = tid >> 6;
    const int l15 = lane & 15, sl = lane >> 4;
    const int bi  = bi0 + w;             // this wave's i (same for all t)

    // ================= phase 0: q-independent prework =================
    {
        const int gid0 = orig * 256 + tid;           // 0..131071
        for (int g = gid0; g < 196608; g += 131072) {   // bases, 1.5 items/thread
            int t = g >> 16, lg = g & 65535;
            const float* W1t = W1 + t*2368;
            int node = lg >> 5, k = lg & 31;
            const float* hn = h + node*32;
            float p = b1[t*32 + k], qq = 0.f;
            #pragma unroll
            for (int f = 0; f < 32; ++f) {
                float hv = hn[f];
                p  += hv * W1t[f*32 + k];
                qq += hv * W1t[(33+f)*32 + k];
            }
            basePbf[g] = __bfloat16_as_ushort(__float2bfloat16(p));
            baseQbf[g] = __bfloat16_as_ushort(__float2bfloat16(qq));
        }
        if (gid0 < 768) {
            // W2 K=16 B-frags (r9-validated pack)
            int tt = gid0 >> 8, lg2 = gid0 & 255;
            int f = lg2 >> 6, ln = lg2 & 63;
            int kh = f >> 1, nt = f & 1;
            int SL = ln >> 4, L15 = ln & 15;
            int k0 = kh*16 + SL*4, n = nt*16 + L15;
            const float* W2t = W2 + tt*1024;
            W2T16[gid0] = make_uint2(
                pkbf2(W2t[k0*32 + n],     W2t[(k0+1)*32 + n]),
                pkbf2(W2t[(k0+2)*32 + n], W2t[(k0+3)*32 + n]));
        } else if (gid0 < 1152) {
            // layer-1 A frags [W1e;I] (r4/r5-validated)
            int g = gid0 - 768;
            int tt = g >> 7, gg = g & 127;
            int kt = gg >> 6, ln = gg & 63;
            int L15 = ln & 15, SL = ln >> 4;
            const float* W1t = W1 + tt*2368;
            float v[8];
            #pragma unroll
            for (int p2 = 0; p2 < 8; ++p2) {
                int d = SL*8 + p2;
                v[p2] = (d < 8) ? W1t[(66+d)*32 + kt*16 + L15]
                                : ((kt*16 + L15 == d - 8) ? 1.0f : 0.0f);
            }
            WA[g] = make_uint4(pkbf2(v[0],v[1]), pkbf2(v[2],v[3]),
                               pkbf2(v[4],v[5]), pkbf2(v[6],v[7]));
        }
    }

    // ---------- t-INVARIANT staging (once; was per-t in r15) ----------
    float maskj = mask[b*256 + j];
    #pragma unroll
    for (int p = 0; p < 4; ++p) {
        const float* ejp = e + ((size_t)(bi0 + p)*256 + j)*8;
        float4 e0 = F4(ejp), e1 = F4(ejp + 4);
        float mx = fmaxf(fmaxf(fmaxf(e0.x,e0.y),fmaxf(e0.z,e0.w)),
                         fmaxf(fmaxf(e1.x,e1.y),fmaxf(e1.z,e1.w)));
        float nearf = (fminf(fmaxf(mx, 1e-8f), 1e5f) != 1e-8f) ? 1.f : 0.f;
        mnL[p][j] = mask[bi0 + p] * maskj * nearf;   // 0.5 applied at the end
        se[p][j] = make_uint4(pkbf2(e0.x,e0.y), pkbf2(e0.z,e0.w),
                              pkbf2(e1.x,e1.y), pkbf2(e1.z,e1.w));
    }
    // t-invariant identity frag (r4-validated)
    U4S8 wa1; wa1.u = make_uint4(0u,0u,0u,0u);
    if (sl == 0 && l15 >= 8) {
        int p = l15 - 8;
        unsigned v = 0x3F80u << ((p & 1) * 16);
        wa1.u.x = ((p>>1)==0)?v:0u;  wa1.u.y = ((p>>1)==1)?v:0u;
        wa1.u.z = ((p>>1)==2)?v:0u;  wa1.u.w = ((p>>1)==3)?v:0u;
    }

    gbar(bar, 512u);    // bases/packs globally visible

    // ================= t loop =================
    for (int t = 0; t < 3; ++t) {
        const float* qsrc = (t == 0) ? q0 : ((t == 1) ? qA : qB);
        float* qdst       = (t == 2) ? qOut : ((t == 0) ? qA : qB);
        const float* W1t   = W1 + t*2368;
        const float* qrowP = W1t + 32*32;
        const float* qrowQ = W1t + 65*32;
        const unsigned short* bP = basePbf + t*65536;
        const unsigned short* bQ = baseQbf + t*65536;
        const uint4* bP4 = (const uint4*)bP;
        const uint4* bQ4 = (const uint4*)bQ;

        // ---- per-t staging: J bases + q_j (safe: gbar preceded us) ----
        {
            const uint4* bq = bQ4 + (size_t)(b*256 + j)*4;
            const uint4* bp = bP4 + (size_t)(b*256 + j)*4;
            sxJ[0][j]=bq[0]; sxJ[1][j]=bq[1]; sxJ[2][j]=bq[2]; sxJ[3][j]=bq[3];
            sxJ[4][j]=bp[0]; sxJ[5][j]=bp[1]; sxJ[6][j]=bp[2]; sxJ[7][j]=bp[3];
        }
        qL[j] = __bfloat16_as_ushort(__float2bfloat16(qsrc[b*256 + j]));

        // ---- per-t hoisted fragments (r15 verbatim) ----
        const uint4* WAt = WA + t*128;
        U4S8 wa00, wa01;
        wa00.u = WAt[lane];
        wa01.u = WAt[64 + lane];
        unsigned aqQ0 = 0, aqQ1 = 0, aqP0 = 0, aqP1 = 0;
        if (sl == 0) {
            aqQ0 = __bfloat16_as_ushort(__float2bfloat16(qrowQ[l15]));
            aqQ1 = __bfloat16_as_ushort(__float2bfloat16(qrowQ[16 + l15]));
            aqP0 = __bfloat16_as_ushort(__float2bfloat16(qrowP[l15]));
            aqP1 = __bfloat16_as_ushort(__float2bfloat16(qrowP[16 + l15]));
        }
        float qi = qsrc[bi];
        const unsigned short* bPi = bP + (size_t)bi*32;
        const unsigned short* bQi = bQ + (size_t)bi*32;
        f32x4 ckP0, ckP1, ckQ0, ckQ1;
        #pragma unroll
        for (int r = 0; r < 4; ++r) {
            int k0 = sl*4 + r, k1 = 16 + sl*4 + r;
            ckP0[r] = bf2f(bPi[k0]) + qi * qrowP[k0];
            ckP1[r] = bf2f(bPi[k1]) + qi * qrowP[k1];
            ckQ0[r] = bf2f(bQi[k0]) + qi * qrowQ[k0];
            ckQ1[r] = bf2f(bQi[k1]) + qi * qrowQ[k1];
        }
        const uint2* W2T16t = W2T16 + t*256;
        U2S4 bu00, bu10, bu01, bu11;
        bu00.u = W2T16t[0*64 + lane];
        bu01.u = W2T16t[1*64 + lane];
        bu10.u = W2T16t[2*64 + lane];
        bu11.u = W2T16t[3*64 + lane];
        float b2v0 = b2[t*32 + l15], b2v1 = b2[t*32 + l15 + 16];
        float w3v0 = W3[t*32 + l15], w3v1 = W3[t*32 + l15 + 16];

        __syncthreads();    // sxJ/qL ready for cross-wave reads

        // ---- hot loop: 16 fragments = all 256 j for this wave's i ----
        float tot = 0.f;
        __builtin_amdgcn_s_setprio(1);
        #pragma unroll 4
        for (int rt = 0; rt < 16; ++rt) {
            const int row = rt*16 + l15;
            unsigned qpk = (sl == 0) ? (unsigned)qL[row] : 0u;
            U4S8 bc2; bc2.u = make_uint4(qpk, 0u, 0u, 0u);
            float pA[4], pB[4];
            #pragma unroll
            for (int dir = 0; dir < 2; ++dir) {
                U4S8 bc0, bc1, aq0, aq1;
                bc0.u = (sl == 0) ? se[w][row]
                                  : (dir ? sxJ[3 + sl][row] : sxJ[sl - 1][row]);
                bc1.u = dir ? sxJ[7][row] : sxJ[3][row];
                aq0.u = make_uint4(dir ? aqP0 : aqQ0, 0u, 0u, 0u);
                aq1.u = make_uint4(dir ? aqP1 : aqQ1, 0u, 0u, 0u);
                f32x4 c0v = dir ? ckQ0 : ckP0;
                f32x4 c1v = dir ? ckQ1 : ckP1;
                // layer-1 (transposed, r5-validated)
                f32x4 dk0 = __builtin_amdgcn_mfma_f32_16x16x32_bf16(wa00.s, bc0.s, c0v, 0,0,0);
                dk0 = __builtin_amdgcn_mfma_f32_16x16x32_bf16(aq0.s, bc2.s, dk0, 0,0,0);
                f32x4 dk1 = __builtin_amdgcn_mfma_f32_16x16x32_bf16(wa01.s, bc0.s, c1v, 0,0,0);
                dk1 = __builtin_amdgcn_mfma_f32_16x16x32_bf16(wa1.s,  bc1.s, dk1, 0,0,0);
                dk1 = __builtin_amdgcn_mfma_f32_16x16x32_bf16(aq1.s,  bc2.s, dk1, 0,0,0);
                // relu+pack -> K=16 A-frags (r9-validated, no exchange)
                U2S4 a0, a1;
                a0.u = make_uint2(pkbf2(fmaxf(dk0[0],0.f), fmaxf(dk0[1],0.f)),
                                  pkbf2(fmaxf(dk0[2],0.f), fmaxf(dk0[3],0.f)));
                a1.u = make_uint2(pkbf2(fmaxf(dk1[0],0.f), fmaxf(dk1[1],0.f)),
                                  pkbf2(fmaxf(dk1[2],0.f), fmaxf(dk1[3],0.f)));
                f32x4 z = {0.f, 0.f, 0.f, 0.f};
                f32x4 d0 = MFMA16(a0.s, bu00.s, z);
                d0 = MFMA16(a1.s, bu10.s, d0);
                f32x4 d1 = MFMA16(a0.s, bu01.s, z);
                d1 = MFMA16(a1.s, bu11.s, d1);
                float* pp = dir ? pB : pA;
                pp[0] = fmaxf(d0[0]+b2v0,0.f)*w3v0 + fmaxf(d1[0]+b2v1,0.f)*w3v1;
                pp[1] = fmaxf(d0[1]+b2v0,0.f)*w3v0 + fmaxf(d1[1]+b2v1,0.f)*w3v1;
                pp[2] = fmaxf(d0[2]+b2v0,0.f)*w3v0 + fmaxf(d1[2]+b2v1,0.f)*w3v1;
                pp[3] = fmaxf(d0[3]+b2v0,0.f)*w3v0 + fmaxf(d1[3]+b2v1,0.f)*w3v1;
            }
            float4 mr = *(const float4*)&mnL[w][rt*16 + sl*4];
            tot += mr.x*(pA[0]-pB[0]) + mr.y*(pA[1]-pB[1])
                 + mr.z*(pA[2]-pB[2]) + mr.w*(pA[3]-pB[3]);
        }
        __builtin_amdgcn_s_setprio(0);

        // wave-local reduction (this wave owns i completely)
        #pragma unroll
        for (int off = 32; off > 0; off >>= 1) tot += __shfl_down(tot, off);
        if (lane == 0)
            qdst[bi] = qsrc[bi] + 0.5f * tot;

        if (t < 2) gbar(bar, 512u * (t + 2));
    }
}

extern "C" void kernel_launch(void* const* d_in, const int* in_sizes, int n_in,
                              void* d_out, int out_size, void* d_ws, size_t ws_size,
                              hipStream_t stream) {
    (void)in_sizes; (void)n_in; (void)out_size; (void)ws_size;
    const float* h    = (const float*)d_in[0];
    const float* e    = (const float*)d_in[1];
    const float* q    = (const float*)d_in[2];
    const float* mask = (const float*)d_in[3];
    const float* W1   = (const float*)d_in[4];
    const float* b1   = (const float*)d_in[5];
    const float* W2   = (const float*)d_in[6];
    const float* b2   = (const float*)d_in[7];
    const float* W3   = (const float*)d_in[8];

    char* ws = (char*)d_ws;
    unsigned short* basePbf = (unsigned short*)ws;            // 384KB
    unsigned short* baseQbf = (unsigned short*)(ws + 393216); // 384KB
    float* qA    = (float*)(ws + 786432);                     // 8KB
    float* qB    = (float*)(ws + 794624);                     // 8KB
    uint2* W2T16 = (uint2*)(ws + 802816);                     // 6KB
    uint4* WA    = (uint4*)(ws + 808960);                     // 6KB
    unsigned* bar = (unsigned*)(ws + 815104);                 // 4B
    float* qOut  = (float*)d_out;

    hipMemsetAsync(bar, 0, sizeof(unsigned), stream);   // capture-legal
    epn_fused<<<512, 256, 0, stream>>>(h, e, q, mask, W1, b1, W2, b2, W3,
                                       basePbf, baseQbf, W2T16, WA,
                                       qA, qB, qOut, bar);
}

// Round 17
// 50.037 us; speedup vs baseline: 4.1969x; 4.1969x over previous
//
#include <hip/hip_runtime.h>
#include <hip/hip_bf16.h>

// EPN layer: B=8, N=256, F=32, E_DIM=8, HID=32, IN_DIM=74, T=3
// ROUND 17 = r14 structure (best, 52.53us) with the layer-1 MFMA chain cut
// from 5 to 2 per dir:
//  - q_j rank-1 term (qrow[k]*q_j): now 8 fp32 FMAs on hoisted fp32 qrow
//    (replaces the aq/bc2 MFMAs; more accurate than bf16 MFMA path).
//  - J[24:32] identity tail (was wa1 MFMA): values are already in the loaded
//    bc1 register (sxJ elems 24..31); lane (sl>=2,r) adds elem sl*4+r-8.
// Rationale: r16 PMC (VALUBusy 11.5%, MfmaUtil 5.3%) shows the body is
// MFMA-latency-chain-bound; removing 2 serialized MFMA latencies per dir
// attacks the critical path directly. Persistence closed (3 failures, gbar
// XCD-L2-invalidate mechanism). Everything else verbatim r14.

typedef __attribute__((ext_vector_type(8))) short short8;
typedef __attribute__((ext_vector_type(4))) short short4v;
typedef __attribute__((ext_vector_type(4))) float f32x4;
union U4S8 { uint4 u; short8 s; };
union U2S4 { uint2 u; short4v s; };
#define F4(p) (*(const float4*)(p))

#if defined(__HIP_DEVICE_COMPILE__)
# if __has_builtin(__builtin_amdgcn_mfma_f32_16x16x16bf16_1k)
#  define MFMA16(a,b,c) __builtin_amdgcn_mfma_f32_16x16x16bf16_1k(a,b,c,0,0,0)
# elif __has_builtin(__builtin_amdgcn_mfma_f32_16x16x16_bf16)
#  define MFMA16(a,b,c) __builtin_amdgcn_mfma_f32_16x16x16_bf16(a,b,c,0,0,0)
# else
#  error "no 16x16x16 bf16 MFMA builtin on this target"
# endif
#else
# define MFMA16(a,b,c) (f32x4{0.f,0.f,0.f,0.f})
#endif

__device__ __forceinline__ unsigned pkbf2(float lo, float hi) {
    unsigned a = __bfloat16_as_ushort(__float2bfloat16(lo));
    unsigned b = __bfloat16_as_ushort(__float2bfloat16(hi));
    return a | (b << 16);
}
__device__ __forceinline__ float bf2f(unsigned short u) {
    return __uint_as_float(((unsigned)u) << 16);
}

// ---- pre: bases for all 3 t + W2 K=16 B-frags + layer-1 A-frags (r9) ----
__global__ __launch_bounds__(256) void epn_pre(
    const float* __restrict__ h, const float* __restrict__ W1,
    const float* __restrict__ b1, const float* __restrict__ W2,
    unsigned short* __restrict__ basePbf, unsigned short* __restrict__ baseQbf,
    uint2* __restrict__ W2T16, uint4* __restrict__ WA)
{
    const int t  = blockIdx.x >> 8;
    const int lg = (blockIdx.x & 255) * 256 + threadIdx.x;  // 0..65535
    const float* W1t = W1 + t*2368;
    if (lg < 256) {
        int f = lg >> 6, lane = lg & 63;
        int kh = f >> 1, nt = f & 1;
        int sl = lane >> 4, l15 = lane & 15;
        int k0 = kh*16 + sl*4, n = nt*16 + l15;
        const float* W2t = W2 + t*1024;
        W2T16[t*256 + lg] = make_uint2(
            pkbf2(W2t[k0*32 + n],     W2t[(k0+1)*32 + n]),
            pkbf2(W2t[(k0+2)*32 + n], W2t[(k0+3)*32 + n]));
    } else if (lg < 384) {
        int g2 = lg - 256;
        int kt = g2 >> 6, lane = g2 & 63;
        int l15 = lane & 15, sl = lane >> 4;
        float v[8];
        #pragma unroll
        for (int p = 0; p < 8; ++p) {
            int d = sl*8 + p;
            v[p] = (d < 8) ? W1t[(66+d)*32 + kt*16 + l15]
                           : ((kt*16 + l15 == d - 8) ? 1.0f : 0.0f);
        }
        WA[t*128 + g2] = make_uint4(pkbf2(v[0],v[1]), pkbf2(v[2],v[3]),
                                    pkbf2(v[4],v[5]), pkbf2(v[6],v[7]));
    }
    const int node = lg >> 5, k = lg & 31;
    const float* hn = h + node*32;
    float p = b1[t*32 + k], qq = 0.f;
    #pragma unroll
    for (int f = 0; f < 32; ++f) {
        float hv = hn[f];
        p  += hv * W1t[f*32 + k];
        qq += hv * W1t[(33+f)*32 + k];
    }
    basePbf[t*65536 + lg] = __bfloat16_as_ushort(__float2bfloat16(p));
    baseQbf[t*65536 + lg] = __bfloat16_as_ushort(__float2bfloat16(qq));
}

// ---- main: one block per (b,i) (XCD-swizzled), both dirs; writes q_dst[bi] ----
__global__ __launch_bounds__(256, 4) void epn_main(
    const float* __restrict__ e, const float* __restrict__ mask,
    const uint4* __restrict__ bP4, const uint4* __restrict__ bQ4,
    const float* __restrict__ qrowP, const float* __restrict__ qrowQ,
    const uint2* __restrict__ W2T16, const uint4* __restrict__ WA,
    const float* __restrict__ b2, const float* __restrict__ W3,
    const float* __restrict__ q_src, float* __restrict__ q_dst)
{
    __shared__ uint4 sx[9][256];   // SoA: slot0=e, 1-4=baseQ, 5-8=baseP (36.9KB)
    __shared__ float mnL[256];
    __shared__ float red[4];

    // XCD-bijective swizzle: XCD k owns batch b=k (2048 = 8*256 exactly)
    const int orig = blockIdx.x;
    const int bi = (orig & 7) * 256 + (orig >> 3);
    const int b = bi >> 8;
    const int tid = threadIdx.x, j = tid;
    const int lane = tid & 63, w = tid >> 6;
    const int l15 = lane & 15, sl = lane >> 4;

    // ---------- staging (all wave-local consumption; no barrier) ----------
    float qj = q_src[b*256 + j];
    unsigned qpk = __bfloat16_as_ushort(__float2bfloat16(qj));
    const float* ejp = e + ((size_t)bi*256 + j)*8;
    float4 e0 = F4(ejp), e1 = F4(ejp + 4);
    float mx = fmaxf(fmaxf(fmaxf(e0.x,e0.y),fmaxf(e0.z,e0.w)),
                     fmaxf(fmaxf(e1.x,e1.y),fmaxf(e1.z,e1.w)));
    float nearf = (fminf(fmaxf(mx, 1e-8f), 1e5f) != 1e-8f) ? 1.f : 0.f;
    mnL[j] = mask[bi] * mask[b*256 + j] * nearf;   // 0.5 applied at the end
    sx[0][j] = make_uint4(pkbf2(e0.x,e0.y), pkbf2(e0.z,e0.w),
                          pkbf2(e1.x,e1.y), pkbf2(e1.z,e1.w));
    {
        const uint4* bq = bQ4 + (size_t)(b*256 + j)*4;
        const uint4* bp = bP4 + (size_t)(b*256 + j)*4;
        sx[1][j]=bq[0]; sx[2][j]=bq[1]; sx[3][j]=bq[2]; sx[4][j]=bq[3];
        sx[5][j]=bp[0]; sx[6][j]=bp[1]; sx[7][j]=bp[2]; sx[8][j]=bp[3];
    }

    // ---------- hoisted fragments ----------
    U4S8 wa00, wa01;
    wa00.u = WA[lane];        // [W1e;I] chunk0, kt=0 (k=0..15)
    wa01.u = WA[64 + lane];   // [W1e;I] chunk0, kt=1 (k=16..31; J[24:32] via VALU)
    // fp32 qrow vectors (q_j rank-1 term now on VALU)
    f32x4 qvQ0, qvQ1, qvP0, qvP1;
    #pragma unroll
    for (int r = 0; r < 4; ++r) {
        qvQ0[r] = qrowQ[sl*4 + r];  qvQ1[r] = qrowQ[16 + sl*4 + r];
        qvP0[r] = qrowP[sl*4 + r];  qvP1[r] = qrowP[16 + sl*4 + r];
    }
    float qi = q_src[bi];
    const unsigned short* bPi = (const unsigned short*)bP4 + (size_t)bi*32;
    const unsigned short* bQi = (const unsigned short*)bQ4 + (size_t)bi*32;
    f32x4 ckP0, ckP1, ckQ0, ckQ1;
    #pragma unroll
    for (int r = 0; r < 4; ++r) {
        int k0 = sl*4 + r, k1 = 16 + sl*4 + r;
        ckP0[r] = bf2f(bPi[k0]) + qi * qrowP[k0];
        ckP1[r] = bf2f(bPi[k1]) + qi * qrowP[k1];
        ckQ0[r] = bf2f(bQi[k0]) + qi * qrowQ[k0];
        ckQ1[r] = bf2f(bQi[k1]) + qi * qrowQ[k1];
    }
    U2S4 bu00, bu10, bu01, bu11;
    bu00.u = W2T16[0*64 + lane];
    bu01.u = W2T16[1*64 + lane];
    bu10.u = W2T16[2*64 + lane];
    bu11.u = W2T16[3*64 + lane];
    float b2v0 = b2[l15], b2v1 = b2[l15+16];
    float w3v0 = W3[l15], w3v1 = W3[l15+16];
    const int slot0_d0 = (sl == 0) ? 0 : sl;        // dir0 chunk0: [e|baseQ]
    const int slot0_d1 = (sl == 0) ? 0 : 4 + sl;    // dir1 chunk0: [e|baseP]
    const bool tailLane = (sl >= 2);                 // k=24..31 holders

    float tot = 0.f;
    __builtin_amdgcn_s_setprio(1);
    #pragma unroll
    for (int rt = 0; rt < 4; ++rt) {
        const int rl  = rt*16 + l15;
        const int row = w*64 + rl;
        unsigned qr = __shfl(qpk, rl);
        float qjv = __uint_as_float(qr << 16);     // q_j as fp32
        float pA[4], pB[4];
        #pragma unroll
        for (int dir = 0; dir < 2; ++dir) {
            U4S8 bc0, bc1;
            bc0.u = sx[dir ? slot0_d1 : slot0_d0][row];
            bc1.u = dir ? sx[8][row] : sx[4][row];   // J[24:32] of row (bf16 x8)
            f32x4 c0v = dir ? ckQ0 : ckP0;
            f32x4 c1v = dir ? ckQ1 : ckP1;
            f32x4 qv0 = dir ? qvP0 : qvQ0;
            f32x4 qv1 = dir ? qvP1 : qvQ1;
            // layer-1 (transposed): 2 MFMAs (was 5)
            f32x4 dk0 = __builtin_amdgcn_mfma_f32_16x16x32_bf16(wa00.s, bc0.s, c0v, 0,0,0);
            f32x4 dk1 = __builtin_amdgcn_mfma_f32_16x16x32_bf16(wa01.s, bc0.s, c1v, 0,0,0);
            // q_j rank-1 term on VALU (fp32 qrow x bf16-rounded q_j)
            #pragma unroll
            for (int r = 0; r < 4; ++r) {
                dk0[r] += qv0[r] * qjv;
                dk1[r] += qv1[r] * qjv;
            }
            // J[24:32] identity tail: lanes sl>=2 add elem sl*4+r-8 of bc1
            {
                unsigned jw0 = (sl == 2) ? bc1.u.x : bc1.u.z;
                unsigned jw1 = (sl == 2) ? bc1.u.y : bc1.u.w;
                float t0 = tailLane ? __uint_as_float(jw0 << 16)          : 0.f;
                float t1 = tailLane ? __uint_as_float(jw0 & 0xFFFF0000u)  : 0.f;
                float t2 = tailLane ? __uint_as_float(jw1 << 16)          : 0.f;
                float t3 = tailLane ? __uint_as_float(jw1 & 0xFFFF0000u)  : 0.f;
                dk1[0] += t0; dk1[1] += t1; dk1[2] += t2; dk1[3] += t3;
            }
            // relu+pack -> K=16 A-frags (r9-validated, no exchange)
            U2S4 a0, a1;
            a0.u = make_uint2(pkbf2(fmaxf(dk0[0],0.f), fmaxf(dk0[1],0.f)),
                              pkbf2(fmaxf(dk0[2],0.f), fmaxf(dk0[3],0.f)));
            a1.u = make_uint2(pkbf2(fmaxf(dk1[0],0.f), fmaxf(dk1[1],0.f)),
                              pkbf2(fmaxf(dk1[2],0.f), fmaxf(dk1[3],0.f)));
            f32x4 z = {0.f, 0.f, 0.f, 0.f};
            f32x4 d0 = MFMA16(a0.s, bu00.s, z);
            d0 = MFMA16(a1.s, bu10.s, d0);
            f32x4 d1 = MFMA16(a0.s, bu01.s, z);
            d1 = MFMA16(a1.s, bu11.s, d1);
            float* pp = dir ? pB : pA;
            pp[0] = fmaxf(d0[0]+b2v0,0.f)*w3v0 + fmaxf(d1[0]+b2v1,0.f)*w3v1;
            pp[1] = fmaxf(d0[1]+b2v0,0.f)*w3v0 + fmaxf(d1[1]+b2v1,0.f)*w3v1;
            pp[2] = fmaxf(d0[2]+b2v0,0.f)*w3v0 + fmaxf(d1[2]+b2v1,0.f)*w3v1;
            pp[3] = fmaxf(d0[3]+b2v0,0.f)*w3v0 + fmaxf(d1[3]+b2v1,0.f)*w3v1;
        }
        // mask factors: wave-local LDS float4
        float4 mr = *(const float4*)&mnL[w*64 + rt*16 + sl*4];
        tot += mr.x*(pA[0]-pB[0]) + mr.y*(pA[1]-pB[1])
             + mr.z*(pA[2]-pB[2]) + mr.w*(pA[3]-pB[3]);
    }
    __builtin_amdgcn_s_setprio(0);
    #pragma unroll
    for (int off = 32; off > 0; off >>= 1) tot += __shfl_down(tot, off);
    if (lane == 0) red[w] = tot;
    __syncthreads();
    if (tid == 0)
        q_dst[bi] = q_src[bi] + 0.5f * (red[0] + red[1] + red[2] + red[3]);
}

extern "C" void kernel_launch(void* const* d_in, const int* in_sizes, int n_in,
                              void* d_out, int out_size, void* d_ws, size_t ws_size,
                              hipStream_t stream) {
    (void)in_sizes; (void)n_in; (void)out_size; (void)ws_size;
    const float* h    = (const float*)d_in[0];
    const float* e    = (const float*)d_in[1];
    const float* q    = (const float*)d_in[2];
    const float* mask = (const float*)d_in[3];
    const float* W1   = (const float*)d_in[4];
    const float* b1   = (const float*)d_in[5];
    const float* W2   = (const float*)d_in[6];
    const float* b2   = (const float*)d_in[7];
    const float* W3   = (const float*)d_in[8];

    char* ws = (char*)d_ws;
    unsigned short* basePbf = (unsigned short*)ws;            // 384KB
    unsigned short* baseQbf = (unsigned short*)(ws + 393216); // 384KB
    float* qA   = (float*)(ws + 786432);                      // 8KB
    float* qB   = (float*)(ws + 794624);                      // 8KB
    uint2* W2T16 = (uint2*)(ws + 802816);                     // 6KB
    uint4* WA    = (uint4*)(ws + 808960);                     // 6KB

    epn_pre<<<768, 256, 0, stream>>>(h, W1, b1, W2, basePbf, baseQbf, W2T16, WA);

    const float* qsrc = q;
    for (int t = 0; t < 3; ++t) {
        float* qdst = (t == 2) ? (float*)d_out : (t == 0 ? qA : qB);
        epn_main<<<2048, 256, 0, stream>>>(
            e, mask,
            (const uint4*)(basePbf + t*65536), (const uint4*)(baseQbf + t*65536),
            W1 + t*2368 + 32*32, W1 + t*2368 + 65*32,
            W2T16 + t*256, WA + t*128,
            b2 + t*32, W3 + t*32, qsrc, qdst);
        qsrc = qdst;
    }
}